// Round 5
// baseline (3777.490 us; speedup 1.0000x reference)
//
#include <hip/hip_runtime.h>
#include <hip/hip_bf16.h>
#include <math.h>

#define NODES 100000
#define EDGES 1200000
#define NG 256

typedef unsigned short u16;
typedef unsigned int   u32;

__device__ __forceinline__ u16 f2bf(float f){
  u32 u = __float_as_uint(f);
  u32 r = (u + 0x7FFFu + ((u >> 16) & 1u)) >> 16;
  return (u16)r;
}
__device__ __forceinline__ float bf2f(u16 b){ return __uint_as_float(((u32)b) << 16); }

// ---------------- utility ----------------
__device__ __forceinline__ float wsum64(float v){
  v += __shfl_xor(v, 32); v += __shfl_xor(v, 16); v += __shfl_xor(v, 8);
  v += __shfl_xor(v, 4);  v += __shfl_xor(v, 2);  v += __shfl_xor(v, 1);
  return v;
}

__device__ __forceinline__ float blockSum128(float v, float* red){
  v = wsum64(v);
  if ((threadIdx.x & 63) == 0) red[threadIdx.x >> 6] = v;
  __syncthreads();
  float r = red[0] + red[1];
  __syncthreads();
  return r;
}

__global__ void k_zero_i(int* p, int n){ int i = blockIdx.x*256 + threadIdx.x; if (i < n) p[i] = 0; }
__global__ void k_zero_f(float* p, int n){ int i = blockIdx.x*256 + threadIdx.x; if (i < n) p[i] = 0.f; }

// ---------------- CSR build ----------------
__global__ void k_hist(const int* __restrict__ dst, int* __restrict__ counts){
  int e = blockIdx.x*256 + threadIdx.x;
  if (e < EDGES) atomicAdd(&counts[dst[e]], 1);
}

__global__ void k_scan1(const int* __restrict__ counts, int* __restrict__ rowptr, int* __restrict__ bsums){
  __shared__ int sd[256];
  int tid = threadIdx.x;
  int base = blockIdx.x*2048 + tid*8;
  int v[8]; int s = 0;
  #pragma unroll
  for (int i = 0; i < 8; i++){
    int idx = base + i;
    int c = (idx < NODES) ? counts[idx] : 0;
    v[i] = s; s += c;
  }
  sd[tid] = s;
  __syncthreads();
  for (int off = 1; off < 256; off <<= 1){
    int t = 0;
    if (tid >= off) t = sd[tid - off];
    __syncthreads();
    if (tid >= off) sd[tid] += t;
    __syncthreads();
  }
  int excl = (tid > 0) ? sd[tid-1] : 0;
  #pragma unroll
  for (int i = 0; i < 8; i++){
    int idx = base + i;
    if (idx < NODES) rowptr[idx] = v[i] + excl;
  }
  if (tid == 255) bsums[blockIdx.x] = sd[255];
}

__global__ void k_scan2(const int* __restrict__ bsums, int* __restrict__ boffs, int nb){
  if (threadIdx.x == 0 && blockIdx.x == 0){
    int run = 0;
    for (int b = 0; b < nb; b++){ boffs[b] = run; run += bsums[b]; }
  }
}

__global__ void k_scan3(int* __restrict__ rowptr, int* __restrict__ cursor, const int* __restrict__ boffs){
  int i = blockIdx.x*256 + threadIdx.x;
  if (i < NODES){
    int r = rowptr[i] + boffs[i >> 11];
    rowptr[i] = r; cursor[i] = r;
  }
  if (i == 0) rowptr[NODES] = EDGES;
}

__global__ void k_scatter(const int* __restrict__ src, const int* __restrict__ dst,
                          int* __restrict__ cursor, int* __restrict__ esrc){
  int e = blockIdx.x*256 + threadIdx.x;
  if (e < EDGES){
    int d = dst[e];
    int p = atomicAdd(&cursor[d], 1);
    esrc[p] = src[e];
  }
}

// ---------------- encoder: h = x@W+b ; z = relu(LN(h)) [z -> bf16] ----------------
__global__ __launch_bounds__(256) void k_enc(const float* __restrict__ x,
    const float* __restrict__ encW, const float* __restrict__ encb,
    const float* __restrict__ lg, const float* __restrict__ lb,
    float* __restrict__ h, u16* __restrict__ z){
  __shared__ float we[320], wb[64], sg[64], sb[64];
  int tid = threadIdx.x;
  for (int i = tid; i < 320; i += 256) we[i] = encW[i];
  if (tid < 64){ wb[tid] = encb[tid]; sg[tid] = lg[tid]; sb[tid] = lb[tid]; }
  __syncthreads();
  int n = blockIdx.x*256 + tid;
  if (n >= NODES) return;
  float xv[5];
  #pragma unroll
  for (int k = 0; k < 5; k++) xv[k] = x[n*5 + k];
  float a[64];
  #pragma unroll
  for (int c = 0; c < 64; c++){
    float t = wb[c];
    #pragma unroll
    for (int k = 0; k < 5; k++) t += xv[k]*we[k*64 + c];
    a[c] = t;
  }
  float mean = 0.f;
  #pragma unroll
  for (int c = 0; c < 64; c++) mean += a[c];
  mean *= (1.f/64.f);
  float var = 0.f;
  #pragma unroll
  for (int c = 0; c < 64; c++){ float d = a[c]-mean; var += d*d; }
  var *= (1.f/64.f);
  float rstd = rsqrtf(var + 1e-5f);
  size_t rb = (size_t)n*64;
  #pragma unroll
  for (int c = 0; c < 64; c += 4){
    *(float4*)&h[rb + c] = make_float4(a[c], a[c+1], a[c+2], a[c+3]);
    ushort4 zv;
    zv.x = f2bf(fmaxf((a[c  ]-mean)*rstd*sg[c  ]+sb[c  ], 0.f));
    zv.y = f2bf(fmaxf((a[c+1]-mean)*rstd*sg[c+1]+sb[c+1], 0.f));
    zv.z = f2bf(fmaxf((a[c+2]-mean)*rstd*sg[c+2]+sb[c+2], 0.f));
    zv.w = f2bf(fmaxf((a[c+3]-mean)*rstd*sg[c+3]+sb[c+3], 0.f));
    *(ushort4*)&z[rb + c] = zv;
  }
}

// ---------------- fused GNN layer: agg (wave/node) + MLP (4 thr/node), all in LDS ----------------
// block = 64 nodes, 256 threads. zin/zout MUST be distinct buffers.
__global__ __launch_bounds__(256, 2) void k_gnn(
    const u16* __restrict__ zin, u16* __restrict__ zout,
    float* __restrict__ h, float* __restrict__ pooled, const int* __restrict__ batch,
    const int* __restrict__ rowptr, const int* __restrict__ esrc,
    const float* __restrict__ tparam, int li, int last,
    const float* __restrict__ W1, const float* __restrict__ B1,
    const float* __restrict__ G1, const float* __restrict__ Q1,
    const float* __restrict__ W2, const float* __restrict__ B2,
    const float* __restrict__ GN, const float* __restrict__ BN){
  __shared__ u16 w1s[64*128];                 // bf16 W1, 16 KB
  __shared__ __align__(16) float w2s[128*64]; // fp32 W2, 32 KB
  __shared__ u16 su[64*68];                   // u (bf16), stride 68 -> conflict-free
  __shared__ u16 sact[64*132];                // act (bf16), stride 132 -> conflict-free
  __shared__ float cb1[128], cg1[128], cq1[128];
  __shared__ float cb2[64], cgn[64], cbn[64];
  int tid = threadIdx.x;
  for (int i = tid; i < 8192; i += 256) w1s[i] = f2bf(W1[i]);
  for (int i = tid; i < 8192; i += 256) w2s[i] = W2[i];
  if (tid < 128){ cb1[tid] = B1[tid]; cg1[tid] = G1[tid]; cq1[tid] = Q1[tid]; }
  if (tid < 64){
    cb2[tid] = B2[tid];
    cgn[tid] = last ? 0.f : GN[tid];
    cbn[tid] = last ? 0.f : BN[tid];
  }
  int base = blockIdx.x*64;
  float tp = tparam[li];
  int wid = tid >> 6, lane = tid & 63;
  // ---- phase 1: softmax aggregation, wave per node (16 nodes per wave) ----
  #pragma unroll 1
  for (int s = 0; s < 16; s++){
    int nl = (s << 2) | wid;
    int n = base + nl;
    if (n < NODES){
      int beg = rowptr[n], end = rowptr[n+1];
      float den = 0.f, num = 0.f;
      int e = beg;
      for (; e + 1 < end; e += 2){
        int s0 = esrc[e], s1 = esrc[e+1];
        float m0 = bf2f(zin[(size_t)s0*64 + lane]) + 1e-7f;
        float m1 = bf2f(zin[(size_t)s1*64 + lane]) + 1e-7f;
        float e0 = __expf(m0*tp), e1 = __expf(m1*tp);
        den += e0 + e1; num += m0*e0 + m1*e1;
      }
      if (e < end){
        int s0 = esrc[e];
        float m0 = bf2f(zin[(size_t)s0*64 + lane]) + 1e-7f;
        float e0 = __expf(m0*tp);
        den += e0; num += m0*e0;
      }
      float agg = num / fmaxf(den, 1e-16f);
      float uval = bf2f(zin[(size_t)n*64 + lane]) + agg;
      su[nl*68 + lane] = f2bf(uval);
    }
  }
  __syncthreads();
  // ---- phase 2: hd = u @ W1 + b1 ; LN128 ; relu -> sact ----
  int nl = tid >> 2, q = tid & 3;
  int n = base + nl;
  bool ok = (n < NODES);
  int jb = q*32;
  float hd[32];
  #pragma unroll
  for (int j = 0; j < 32; j++) hd[j] = cb1[jb + j];
  if (ok){
    const u32* w1p = (const u32*)w1s;
    #pragma unroll 2
    for (int k = 0; k < 64; k++){
      float uk = bf2f(su[nl*68 + k]);
      int rb0 = (k*128 + jb) >> 1;
      #pragma unroll
      for (int p = 0; p < 16; p++){
        u32 wv = w1p[rb0 + p];
        hd[p*2  ] += uk*__uint_as_float(wv << 16);
        hd[p*2+1] += uk*__uint_as_float(wv & 0xFFFF0000u);
      }
    }
  }
  float s1 = 0.f;
  #pragma unroll
  for (int j = 0; j < 32; j++) s1 += hd[j];
  s1 += __shfl_xor(s1, 1); s1 += __shfl_xor(s1, 2);
  float mean = s1*(1.f/128.f);
  float vs = 0.f;
  #pragma unroll
  for (int j = 0; j < 32; j++){ float d = hd[j]-mean; vs += d*d; }
  vs += __shfl_xor(vs, 1); vs += __shfl_xor(vs, 2);
  float rstd = rsqrtf(vs*(1.f/128.f) + 1e-5f);
  if (ok){
    u32* sap = (u32*)&sact[nl*132 + jb];
    #pragma unroll
    for (int j2 = 0; j2 < 16; j2++){
      u16 lo = f2bf(fmaxf((hd[j2*2  ]-mean)*rstd*cg1[jb+j2*2  ] + cq1[jb+j2*2  ], 0.f));
      u16 hi = f2bf(fmaxf((hd[j2*2+1]-mean)*rstd*cg1[jb+j2*2+1] + cq1[jb+j2*2+1], 0.f));
      sap[j2] = (u32)lo | ((u32)hi << 16);
    }
  }
  __syncthreads();
  // ---- phase 3: out = act @ W2 + b2 ; h += ; znext = relu(LN64) or pool ----
  int cb = q*16;
  float out[16];
  #pragma unroll
  for (int c = 0; c < 16; c++) out[c] = cb2[cb + c];
  if (!ok) return;
  {
    const u32* sap = (const u32*)&sact[nl*132];
    #pragma unroll 2
    for (int m2 = 0; m2 < 64; m2++){
      u32 av = sap[m2];
      float a0 = __uint_as_float(av << 16);
      float a1 = __uint_as_float(av & 0xFFFF0000u);
      const float4* wr0 = (const float4*)&w2s[(m2*2  )*64 + cb];
      const float4* wr1 = (const float4*)&w2s[(m2*2+1)*64 + cb];
      #pragma unroll
      for (int c4 = 0; c4 < 4; c4++){
        float4 w0 = wr0[c4], w1 = wr1[c4];
        out[c4*4  ] += a0*w0.x + a1*w1.x;
        out[c4*4+1] += a0*w0.y + a1*w1.y;
        out[c4*4+2] += a0*w0.z + a1*w1.z;
        out[c4*4+3] += a0*w0.w + a1*w1.w;
      }
    }
  }
  size_t rb = (size_t)n*64 + cb;
  #pragma unroll
  for (int c4 = 0; c4 < 4; c4++){
    float4 hv = *(const float4*)&h[rb + c4*4];
    out[c4*4  ] += hv.x; out[c4*4+1] += hv.y;
    out[c4*4+2] += hv.z; out[c4*4+3] += hv.w;
  }
  if (!last){
    #pragma unroll
    for (int c4 = 0; c4 < 4; c4++)
      *(float4*)&h[rb + c4*4] = make_float4(out[c4*4], out[c4*4+1], out[c4*4+2], out[c4*4+3]);
    float s2 = 0.f;
    #pragma unroll
    for (int c = 0; c < 16; c++) s2 += out[c];
    s2 += __shfl_xor(s2, 1); s2 += __shfl_xor(s2, 2);
    float m2v = s2*(1.f/64.f);
    float v2 = 0.f;
    #pragma unroll
    for (int c = 0; c < 16; c++){ float d = out[c]-m2v; v2 += d*d; }
    v2 += __shfl_xor(v2, 1); v2 += __shfl_xor(v2, 2);
    float rs2 = rsqrtf(v2*(1.f/64.f) + 1e-5f);
    u32 pk[8];
    #pragma unroll
    for (int c2 = 0; c2 < 8; c2++){
      u16 lo = f2bf(fmaxf((out[c2*2  ]-m2v)*rs2*cgn[cb+c2*2  ] + cbn[cb+c2*2  ], 0.f));
      u16 hi = f2bf(fmaxf((out[c2*2+1]-m2v)*rs2*cgn[cb+c2*2+1] + cbn[cb+c2*2+1], 0.f));
      pk[c2] = (u32)lo | ((u32)hi << 16);
    }
    uint4* zp = (uint4*)&zout[rb];
    zp[0] = make_uint4(pk[0], pk[1], pk[2], pk[3]);
    zp[1] = make_uint4(pk[4], pk[5], pk[6], pk[7]);
  } else {
    int g = batch[n];
    #pragma unroll
    for (int c = 0; c < 16; c++) atomicAdd(&pooled[g*64 + cb + c], out[c]);
  }
}

// ---------------- pooled + var MLP -> t ; qkv for layer 0 ----------------
__global__ __launch_bounds__(128) void k_pool2(
    const float* __restrict__ pooled, const float* __restrict__ var_data,
    const float* __restrict__ v1W, const float* __restrict__ v1b,
    const float* __restrict__ v2W, const float* __restrict__ v2b,
    const float* __restrict__ v3W, const float* __restrict__ v3b,
    float* __restrict__ t, float* __restrict__ qkvout,
    const float* __restrict__ qW, const float* __restrict__ qb){
  __shared__ float vin[19], l1[16], l2[32], tr[128];
  int c = threadIdx.x, s = blockIdx.x;
  if (c < 19) vin[c] = var_data[s*19 + c];
  __syncthreads();
  if (c < 16){
    float a = v1b[c];
    for (int k = 0; k < 19; k++) a += vin[k]*v1W[k*16 + c];
    l1[c] = fmaxf(a, 0.f);
  }
  __syncthreads();
  if (c < 32){
    float a = v2b[c];
    for (int k = 0; k < 16; k++) a += l1[k]*v2W[k*32 + c];
    l2[c] = fmaxf(a, 0.f);
  }
  __syncthreads();
  float tv;
  if (c < 64) tv = pooled[s*64 + c];
  else {
    float a = v3b[c-64];
    for (int k = 0; k < 32; k++) a += l2[k]*v3W[k*64 + (c-64)];
    tv = a;
  }
  tr[c] = tv; t[s*128 + c] = tv;
  __syncthreads();
  #pragma unroll 1
  for (int r = 0; r < 3; r++){
    int col = r*128 + c;
    float a = qb[col];
    #pragma unroll 4
    for (int k = 0; k < 128; k++) a += tr[k]*qW[k*384 + col];
    qkvout[s*384 + col] = a;
  }
}

// ---------------- attention (8 heads, S=256, dh=16) ----------------
__global__ __launch_bounds__(256) void k_att(const float* __restrict__ qkv, float* __restrict__ oatt){
  __shared__ float kb[256*16];
  __shared__ float vb[256*16];
  int tid = threadIdx.x;
  int head = blockIdx.x >> 3;
  int tile = blockIdx.x & 7;
  int hb = head*16;
  for (int i = tid; i < 4096; i += 256){
    int s = i >> 4, d = i & 15;
    kb[i] = qkv[s*384 + 128 + hb + d];
    vb[i] = qkv[s*384 + 256 + hb + d];
  }
  __syncthreads();
  int row = tile*32 + (tid >> 3);
  int sub = tid & 7;
  float q[16];
  #pragma unroll
  for (int d = 0; d < 16; d++) q[d] = qkv[row*384 + hb + d];
  float sc[32];
  int k0 = sub*32;
  #pragma unroll
  for (int kk = 0; kk < 32; kk++){
    const float* kr = &kb[(k0+kk)*16];
    float s = 0.f;
    #pragma unroll
    for (int d = 0; d < 16; d++) s += q[d]*kr[d];
    sc[kk] = s*0.25f;
  }
  float m = -1e30f;
  #pragma unroll
  for (int kk = 0; kk < 32; kk++) m = fmaxf(m, sc[kk]);
  m = fmaxf(m, __shfl_xor(m, 1)); m = fmaxf(m, __shfl_xor(m, 2)); m = fmaxf(m, __shfl_xor(m, 4));
  float sum = 0.f;
  #pragma unroll
  for (int kk = 0; kk < 32; kk++){ sc[kk] = __expf(sc[kk]-m); sum += sc[kk]; }
  sum += __shfl_xor(sum, 1); sum += __shfl_xor(sum, 2); sum += __shfl_xor(sum, 4);
  float o[16];
  #pragma unroll
  for (int d = 0; d < 16; d++) o[d] = 0.f;
  #pragma unroll
  for (int kk = 0; kk < 32; kk++){
    const float* vr = &vb[(k0+kk)*16];
    float p = sc[kk];
    #pragma unroll
    for (int d = 0; d < 16; d++) o[d] += p*vr[d];
  }
  float inv = 1.f/sum;
  #pragma unroll
  for (int d = 0; d < 16; d++){
    float tv = o[d];
    tv += __shfl_xor(tv, 1); tv += __shfl_xor(tv, 2); tv += __shfl_xor(tv, 4);
    if (sub == 0) oatt[row*128 + hb + d] = tv*inv;
  }
}

// ---------------- encoder row-local: oproj+LN1+FF+LN2 (+ next qkv / head) ----------------
__global__ __launch_bounds__(128) void k_row(
    const float* __restrict__ oatt, float* __restrict__ t, float* __restrict__ qkvout,
    const float* __restrict__ outW, const float* __restrict__ outb,
    const float* __restrict__ l1g, const float* __restrict__ l1b,
    const float* __restrict__ f1W, const float* __restrict__ f1b,
    const float* __restrict__ f2W, const float* __restrict__ f2b,
    const float* __restrict__ l2g, const float* __restrict__ l2b,
    const float* __restrict__ qW, const float* __restrict__ qb,
    const float* __restrict__ hW, const float* __restrict__ hb2,
    float* __restrict__ dout, int last){
  __shared__ float so[128], st[128], s1[128], sf[128];
  __shared__ float red[2];
  int c = threadIdx.x, s = blockIdx.x;
  so[c] = oatt[s*128 + c];
  st[c] = t[s*128 + c];
  __syncthreads();
  float acc = outb[c];
  #pragma unroll 4
  for (int k = 0; k < 128; k++) acc += so[k]*outW[k*128 + c];
  acc += st[c];
  float mean = blockSum128(acc, red)*(1.f/128.f);
  float d0 = acc - mean;
  float var = blockSum128(d0*d0, red)*(1.f/128.f);
  float t1 = d0*rsqrtf(var + 1e-5f)*l1g[c] + l1b[c];
  s1[c] = t1;
  __syncthreads();
  float f = f1b[c];
  #pragma unroll 4
  for (int k = 0; k < 128; k++) f += s1[k]*f1W[k*128 + c];
  f = 0.5f*f*(1.f + erff(f*0.70710678118654752f));
  sf[c] = f;
  __syncthreads();
  float g = f2b[c];
  #pragma unroll 4
  for (int k = 0; k < 128; k++) g += sf[k]*f2W[k*128 + c];
  g += t1;
  float mean2 = blockSum128(g, red)*(1.f/128.f);
  float d2 = g - mean2;
  float var2 = blockSum128(d2*d2, red)*(1.f/128.f);
  float t2 = d2*rsqrtf(var2 + 1e-5f)*l2g[c] + l2b[c];
  t[s*128 + c] = t2;
  __syncthreads();
  s1[c] = t2;
  __syncthreads();
  if (!last){
    #pragma unroll 1
    for (int r = 0; r < 3; r++){
      int col = r*128 + c;
      float a = qb[col];
      #pragma unroll 4
      for (int k = 0; k < 128; k++) a += s1[k]*qW[k*384 + col];
      qkvout[s*384 + col] = a;
    }
  } else {
    if (c < 2){
      float a = hb2[c];
      for (int k = 0; k < 128; k++) a += s1[k]*hW[k*2 + c];
      dout[s*2 + c] = a;
    }
  }
}

// ---------------- host ----------------
extern "C" void kernel_launch(void* const* d_in, const int* in_sizes, int n_in,
                              void* d_out, int out_size, void* d_ws, size_t ws_size,
                              hipStream_t stream){
  const float* x       = (const float*)d_in[0];
  const int*   ei      = (const int*)  d_in[1];
  const int*   batch   = (const int*)  d_in[2];
  const float* var_d   = (const float*)d_in[3];
  const float* encW    = (const float*)d_in[4];
  const float* encb    = (const float*)d_in[5];
  const float* ln_g    = (const float*)d_in[6];
  const float* ln_b    = (const float*)d_in[7];
  const float* tparam  = (const float*)d_in[8];
  const float* m1W     = (const float*)d_in[9];
  const float* m1b     = (const float*)d_in[10];
  const float* mng     = (const float*)d_in[11];
  const float* mnb     = (const float*)d_in[12];
  const float* m2W     = (const float*)d_in[13];
  const float* m2b     = (const float*)d_in[14];
  const float* v1W     = (const float*)d_in[15];
  const float* v1b     = (const float*)d_in[16];
  const float* v2W     = (const float*)d_in[17];
  const float* v2b     = (const float*)d_in[18];
  const float* v3W     = (const float*)d_in[19];
  const float* v3b     = (const float*)d_in[20];
  const float* qkvW    = (const float*)d_in[21];
  const float* qkvB    = (const float*)d_in[22];
  const float* outW    = (const float*)d_in[23];
  const float* outb    = (const float*)d_in[24];
  const float* l1g     = (const float*)d_in[25];
  const float* l1b     = (const float*)d_in[26];
  const float* f1W     = (const float*)d_in[27];
  const float* f1b     = (const float*)d_in[28];
  const float* f2W     = (const float*)d_in[29];
  const float* f2b     = (const float*)d_in[30];
  const float* l2g     = (const float*)d_in[31];
  const float* l2b     = (const float*)d_in[32];
  const float* headW   = (const float*)d_in[33];
  const float* headB   = (const float*)d_in[34];
  float* dout = (float*)d_out;

  char* wsb = (char*)d_ws;
  size_t off = 0;
  auto nxt = [&](size_t bytes)->void*{
    void* p = wsb + off;
    off += (bytes + 255) & ~(size_t)255;
    return p;
  };
  float* h      = (float*)nxt((size_t)NODES*64*4);
  u16*   z0     = (u16*)  nxt((size_t)NODES*64*2);
  u16*   z1     = (u16*)  nxt((size_t)NODES*64*2);
  int*   rowptr = (int*)  nxt((size_t)(NODES+1)*4);
  int*   cursor = (int*)  nxt((size_t)NODES*4);
  int*   counts = (int*)  nxt((size_t)NODES*4);
  int*   bsums  = (int*)  nxt(64*4);
  int*   boffs  = (int*)  nxt(64*4);
  int*   esrc   = (int*)  nxt((size_t)EDGES*4);
  float* pooled = (float*)nxt((size_t)NG*64*4);
  float* tbuf   = (float*)nxt((size_t)NG*128*4);
  float* qkvb   = (float*)nxt((size_t)NG*384*4);
  float* oatt   = (float*)nxt((size_t)NG*128*4);
  u16*   zb[2]  = { z0, z1 };

  const int* srcp = ei;
  const int* dstp = ei + EDGES;

  k_zero_i <<<391, 256, 0, stream>>>(counts, NODES);
  k_hist   <<<4688, 256, 0, stream>>>(dstp, counts);
  k_scan1  <<<49, 256, 0, stream>>>(counts, rowptr, bsums);
  k_scan2  <<<1, 64, 0, stream>>>(bsums, boffs, 49);
  k_scan3  <<<391, 256, 0, stream>>>(rowptr, cursor, boffs);
  k_scatter<<<4688, 256, 0, stream>>>(srcp, dstp, cursor, esrc);
  k_zero_f <<<64, 256, 0, stream>>>(pooled, NG*64);
  k_enc    <<<391, 256, 0, stream>>>(x, encW, encb, ln_g, ln_b, h, z0);

  for (int i = 0; i < 6; i++){
    int last = (i == 5);
    k_gnn<<<1563, 256, 0, stream>>>(zb[i & 1], zb[(i + 1) & 1], h, pooled, batch,
        rowptr, esrc, tparam, i, last,
        m1W + i*8192, m1b + i*128, mng + i*128, mnb + i*128,
        m2W + i*8192, m2b + i*64,
        ln_g + (last ? 0 : (i+1)*64), ln_b + (last ? 0 : (i+1)*64));
  }

  k_pool2<<<NG, 128, 0, stream>>>(pooled, var_d, v1W, v1b, v2W, v2b, v3W, v3b,
                                  tbuf, qkvb, qkvW, qkvB);

  for (int i = 0; i < 6; i++){
    int last = (i == 5);
    k_att<<<64, 256, 0, stream>>>(qkvb, oatt);
    k_row<<<NG, 128, 0, stream>>>(oatt, tbuf, qkvb,
        outW + i*16384, outb + i*128, l1g + i*128, l1b + i*128,
        f1W + i*16384, f1b + i*128, f2W + i*16384, f2b + i*128,
        l2g + i*128, l2b + i*128,
        qkvW + (size_t)(last ? 0 : (i+1))*49152, qkvB + (last ? 0 : (i+1))*384,
        headW, headB, dout, last);
  }
}

// Round 6
// 2352.458 us; speedup vs baseline: 1.6058x; 1.6058x over previous
//
#include <hip/hip_runtime.h>
#include <hip/hip_bf16.h>
#include <math.h>

#define NODES 100000
#define EDGES 1200000
#define NG 256

typedef unsigned short u16;
typedef unsigned int   u32;

__device__ __forceinline__ u16 f2bf(float f){
  u32 u = __float_as_uint(f);
  u32 r = (u + 0x7FFFu + ((u >> 16) & 1u)) >> 16;
  return (u16)r;
}
__device__ __forceinline__ float bf2f(u16 b){ return __uint_as_float(((u32)b) << 16); }

// ---------------- utility ----------------
__device__ __forceinline__ float wsum64(float v){
  v += __shfl_xor(v, 32); v += __shfl_xor(v, 16); v += __shfl_xor(v, 8);
  v += __shfl_xor(v, 4);  v += __shfl_xor(v, 2);  v += __shfl_xor(v, 1);
  return v;
}
__device__ __forceinline__ float wmax64(float v){
  v = fmaxf(v, __shfl_xor(v, 32)); v = fmaxf(v, __shfl_xor(v, 16));
  v = fmaxf(v, __shfl_xor(v, 8));  v = fmaxf(v, __shfl_xor(v, 4));
  v = fmaxf(v, __shfl_xor(v, 2));  v = fmaxf(v, __shfl_xor(v, 1));
  return v;
}

// 256-thread block sum (inactive threads pass 0)
__device__ __forceinline__ float bsum256(float v, float* red){
  v = wsum64(v);
  if ((threadIdx.x & 63) == 0) red[threadIdx.x >> 6] = v;
  __syncthreads();
  float r = red[0] + red[1] + red[2] + red[3];
  __syncthreads();
  return r;
}

__global__ void k_zero_i(int* p, int n){ int i = blockIdx.x*256 + threadIdx.x; if (i < n) p[i] = 0; }
__global__ void k_zero_f(float* p, int n){ int i = blockIdx.x*256 + threadIdx.x; if (i < n) p[i] = 0.f; }

// ---------------- CSR build ----------------
__global__ void k_hist(const int* __restrict__ dst, int* __restrict__ counts){
  int e = blockIdx.x*256 + threadIdx.x;
  if (e < EDGES) atomicAdd(&counts[dst[e]], 1);
}

__global__ void k_scan1(const int* __restrict__ counts, int* __restrict__ rowptr, int* __restrict__ bsums){
  __shared__ int sd[256];
  int tid = threadIdx.x;
  int base = blockIdx.x*2048 + tid*8;
  int v[8]; int s = 0;
  #pragma unroll
  for (int i = 0; i < 8; i++){
    int idx = base + i;
    int c = (idx < NODES) ? counts[idx] : 0;
    v[i] = s; s += c;
  }
  sd[tid] = s;
  __syncthreads();
  for (int off = 1; off < 256; off <<= 1){
    int t = 0;
    if (tid >= off) t = sd[tid - off];
    __syncthreads();
    if (tid >= off) sd[tid] += t;
    __syncthreads();
  }
  int excl = (tid > 0) ? sd[tid-1] : 0;
  #pragma unroll
  for (int i = 0; i < 8; i++){
    int idx = base + i;
    if (idx < NODES) rowptr[idx] = v[i] + excl;
  }
  if (tid == 255) bsums[blockIdx.x] = sd[255];
}

__global__ void k_scan2(const int* __restrict__ bsums, int* __restrict__ boffs, int nb){
  if (threadIdx.x == 0 && blockIdx.x == 0){
    int run = 0;
    for (int b = 0; b < nb; b++){ boffs[b] = run; run += bsums[b]; }
  }
}

__global__ void k_scan3(int* __restrict__ rowptr, int* __restrict__ cursor, const int* __restrict__ boffs){
  int i = blockIdx.x*256 + threadIdx.x;
  if (i < NODES){
    int r = rowptr[i] + boffs[i >> 11];
    rowptr[i] = r; cursor[i] = r;
  }
  if (i == 0) rowptr[NODES] = EDGES;
}

__global__ void k_scatter(const int* __restrict__ src, const int* __restrict__ dst,
                          int* __restrict__ cursor, int* __restrict__ esrc){
  int e = blockIdx.x*256 + threadIdx.x;
  if (e < EDGES){
    int d = dst[e];
    int p = atomicAdd(&cursor[d], 1);
    esrc[p] = src[e];
  }
}

// ---------------- encoder: h = x@W+b ; z = relu(LN(h)) [z -> bf16] ----------------
__global__ __launch_bounds__(256) void k_enc(const float* __restrict__ x,
    const float* __restrict__ encW, const float* __restrict__ encb,
    const float* __restrict__ lg, const float* __restrict__ lb,
    float* __restrict__ h, u16* __restrict__ z){
  __shared__ float we[320], wb[64], sg[64], sb[64];
  int tid = threadIdx.x;
  for (int i = tid; i < 320; i += 256) we[i] = encW[i];
  if (tid < 64){ wb[tid] = encb[tid]; sg[tid] = lg[tid]; sb[tid] = lb[tid]; }
  __syncthreads();
  int n = blockIdx.x*256 + tid;
  if (n >= NODES) return;
  float xv[5];
  #pragma unroll
  for (int k = 0; k < 5; k++) xv[k] = x[n*5 + k];
  float a[64];
  #pragma unroll
  for (int c = 0; c < 64; c++){
    float t = wb[c];
    #pragma unroll
    for (int k = 0; k < 5; k++) t += xv[k]*we[k*64 + c];
    a[c] = t;
  }
  float mean = 0.f;
  #pragma unroll
  for (int c = 0; c < 64; c++) mean += a[c];
  mean *= (1.f/64.f);
  float var = 0.f;
  #pragma unroll
  for (int c = 0; c < 64; c++){ float d = a[c]-mean; var += d*d; }
  var *= (1.f/64.f);
  float rstd = rsqrtf(var + 1e-5f);
  size_t rb = (size_t)n*64;
  #pragma unroll
  for (int c = 0; c < 64; c += 4){
    *(float4*)&h[rb + c] = make_float4(a[c], a[c+1], a[c+2], a[c+3]);
    ushort4 zv;
    zv.x = f2bf(fmaxf((a[c  ]-mean)*rstd*sg[c  ]+sb[c  ], 0.f));
    zv.y = f2bf(fmaxf((a[c+1]-mean)*rstd*sg[c+1]+sb[c+1], 0.f));
    zv.z = f2bf(fmaxf((a[c+2]-mean)*rstd*sg[c+2]+sb[c+2], 0.f));
    zv.w = f2bf(fmaxf((a[c+3]-mean)*rstd*sg[c+3]+sb[c+3], 0.f));
    *(ushort4*)&z[rb + c] = zv;
  }
}

// ---------------- GENConv softmax aggregation: u = z + agg [bf16 in/out] ----------------
__global__ __launch_bounds__(256) void k_agg(const u16* __restrict__ z, u16* __restrict__ u,
    const int* __restrict__ rowptr, const int* __restrict__ esrc,
    const float* __restrict__ tparam, int li){
  int lane = threadIdx.x & 63;
  int n = blockIdx.x*4 + (threadIdx.x >> 6);
  if (n >= NODES) return;
  float tp = tparam[li];
  int beg = rowptr[n], end = rowptr[n+1];
  float den = 0.f, num = 0.f;
  int e = beg;
  for (; e + 3 < end; e += 4){           // 4-way ILP on the gather chain
    int s0 = esrc[e], s1 = esrc[e+1], s2 = esrc[e+2], s3 = esrc[e+3];
    float m0 = bf2f(z[(size_t)s0*64 + lane]) + 1e-7f;
    float m1 = bf2f(z[(size_t)s1*64 + lane]) + 1e-7f;
    float m2 = bf2f(z[(size_t)s2*64 + lane]) + 1e-7f;
    float m3 = bf2f(z[(size_t)s3*64 + lane]) + 1e-7f;
    float e0 = __expf(m0*tp), e1 = __expf(m1*tp), e2 = __expf(m2*tp), e3 = __expf(m3*tp);
    den += (e0 + e1) + (e2 + e3);
    num += (m0*e0 + m1*e1) + (m2*e2 + m3*e3);
  }
  for (; e < end; ++e){
    int s0 = esrc[e];
    float m0 = bf2f(z[(size_t)s0*64 + lane]) + 1e-7f;
    float e0 = __expf(m0*tp);
    den += e0; num += m0*e0;
  }
  float agg = num / fmaxf(den, 1e-16f);
  float zn = bf2f(z[(size_t)n*64 + lane]);
  u[(size_t)n*64 + lane] = f2bf(zn + agg);
}

// ---------------- MLP part A: act = relu(LN(u @ W1 + b1)) ----------------
// 128 nodes/block, 256 threads; thread (nl,q) computes nodes nl and nl+64, outputs [q*32, q*32+32).
__global__ __launch_bounds__(256) void k_mlpa(
    const u16* __restrict__ u, u16* __restrict__ act,
    const float* __restrict__ W1, const float* __restrict__ B1,
    const float* __restrict__ G1, const float* __restrict__ Q1){
  __shared__ u16 w1s[64*128];                 // bf16 W1, 16 KB
  __shared__ u16 su[128*68];                  // bf16 u tile, 17.4 KB
  __shared__ float cb1[128], cg1[128], cq1[128];
  int tid = threadIdx.x;
  for (int i = tid; i < 8192; i += 256) w1s[i] = f2bf(W1[i]);
  if (tid < 128){ cb1[tid] = B1[tid]; cg1[tid] = G1[tid]; cq1[tid] = Q1[tid]; }
  int base = blockIdx.x*128;
  int nval = NODES - base; if (nval > 128) nval = 128; if (nval < 0) nval = 0;
  const u32* up = (const u32*)u;
  u32* sp = (u32*)su;
  for (int i = tid; i < nval*32; i += 256){
    int node = i >> 5, c2 = i & 31;
    sp[node*34 + c2] = up[(size_t)(base + node)*32 + c2];
  }
  __syncthreads();
  int nl = tid >> 2, q = tid & 3, jb = q*32;
  bool okA = (base + nl      < NODES);
  bool okB = (base + nl + 64 < NODES);
  float hA[32], hB[32];
  #pragma unroll
  for (int j = 0; j < 32; j++){ hA[j] = cb1[jb + j]; hB[j] = hA[j]; }
  const u32* w1p = (const u32*)w1s;
  #pragma unroll 2
  for (int k = 0; k < 64; k++){
    float ua = bf2f(su[nl*68 + k]);
    float ub = bf2f(su[(nl+64)*68 + k]);
    int rb0 = (k*128 + jb) >> 1;
    #pragma unroll
    for (int p = 0; p < 16; p++){
      u32 wv = w1p[rb0 + p];
      float w0 = __uint_as_float(wv << 16);
      float w1v = __uint_as_float(wv & 0xFFFF0000u);
      hA[p*2  ] += ua*w0; hA[p*2+1] += ua*w1v;
      hB[p*2  ] += ub*w0; hB[p*2+1] += ub*w1v;
    }
  }
  // LN over 128 per node (quad reduce), relu, store bf16
  {
    float s = 0.f;
    #pragma unroll
    for (int j = 0; j < 32; j++) s += hA[j];
    s += __shfl_xor(s, 1); s += __shfl_xor(s, 2);
    float mean = s*(1.f/128.f);
    float vs = 0.f;
    #pragma unroll
    for (int j = 0; j < 32; j++){ float d = hA[j]-mean; vs += d*d; }
    vs += __shfl_xor(vs, 1); vs += __shfl_xor(vs, 2);
    float rstd = rsqrtf(vs*(1.f/128.f) + 1e-5f);
    if (okA){
      u32 pk[16];
      #pragma unroll
      for (int j2 = 0; j2 < 16; j2++){
        u16 lo = f2bf(fmaxf((hA[j2*2  ]-mean)*rstd*cg1[jb+j2*2  ] + cq1[jb+j2*2  ], 0.f));
        u16 hi = f2bf(fmaxf((hA[j2*2+1]-mean)*rstd*cg1[jb+j2*2+1] + cq1[jb+j2*2+1], 0.f));
        pk[j2] = (u32)lo | ((u32)hi << 16);
      }
      uint4* ap = (uint4*)(act + (size_t)(base+nl)*128 + jb);
      ap[0] = make_uint4(pk[0],pk[1],pk[2],pk[3]);
      ap[1] = make_uint4(pk[4],pk[5],pk[6],pk[7]);
      ap[2] = make_uint4(pk[8],pk[9],pk[10],pk[11]);
      ap[3] = make_uint4(pk[12],pk[13],pk[14],pk[15]);
    }
  }
  {
    float s = 0.f;
    #pragma unroll
    for (int j = 0; j < 32; j++) s += hB[j];
    s += __shfl_xor(s, 1); s += __shfl_xor(s, 2);
    float mean = s*(1.f/128.f);
    float vs = 0.f;
    #pragma unroll
    for (int j = 0; j < 32; j++){ float d = hB[j]-mean; vs += d*d; }
    vs += __shfl_xor(vs, 1); vs += __shfl_xor(vs, 2);
    float rstd = rsqrtf(vs*(1.f/128.f) + 1e-5f);
    if (okB){
      u32 pk[16];
      #pragma unroll
      for (int j2 = 0; j2 < 16; j2++){
        u16 lo = f2bf(fmaxf((hB[j2*2  ]-mean)*rstd*cg1[jb+j2*2  ] + cq1[jb+j2*2  ], 0.f));
        u16 hi = f2bf(fmaxf((hB[j2*2+1]-mean)*rstd*cg1[jb+j2*2+1] + cq1[jb+j2*2+1], 0.f));
        pk[j2] = (u32)lo | ((u32)hi << 16);
      }
      uint4* ap = (uint4*)(act + (size_t)(base+nl+64)*128 + jb);
      ap[0] = make_uint4(pk[0],pk[1],pk[2],pk[3]);
      ap[1] = make_uint4(pk[4],pk[5],pk[6],pk[7]);
      ap[2] = make_uint4(pk[8],pk[9],pk[10],pk[11]);
      ap[3] = make_uint4(pk[12],pk[13],pk[14],pk[15]);
    }
  }
}

// ---------------- MLP part B: h += act @ W2 + b2 ; znext or pool [bf16 W2] ----------------
__global__ __launch_bounds__(256) void k_mlpb(
    const u16* __restrict__ act, float* __restrict__ h, u16* __restrict__ znext,
    float* __restrict__ pooled, const int* __restrict__ batch,
    const float* __restrict__ W2, const float* __restrict__ B2,
    const float* __restrict__ GN, const float* __restrict__ BN,
    int last){
  __shared__ u16 w2s[128*64];                 // bf16 W2, 16 KB
  __shared__ float cb2[64], cgn[64], cbn[64];
  int tid = threadIdx.x;
  for (int i = tid; i < 8192; i += 256) w2s[i] = f2bf(W2[i]);
  if (tid < 64){
    cb2[tid] = B2[tid];
    cgn[tid] = last ? 0.f : GN[tid];
    cbn[tid] = last ? 0.f : BN[tid];
  }
  __syncthreads();
  int gid = blockIdx.x*256 + tid;
  int n = gid >> 2;
  int q = gid & 3;
  if (n >= NODES) return;
  int cb = q*16;
  float out[16];
  #pragma unroll
  for (int c = 0; c < 16; c++) out[c] = cb2[cb + c];
  const uint4* arowv = (const uint4*)(act + (size_t)n*128);
  const uint4* w2q = (const uint4*)w2s;
  #pragma unroll 2
  for (int m8 = 0; m8 < 16; m8++){
    uint4 av = arowv[m8];
    float aa[8];
    aa[0] = bf2f((u16)(av.x & 0xFFFFu)); aa[1] = bf2f((u16)(av.x >> 16));
    aa[2] = bf2f((u16)(av.y & 0xFFFFu)); aa[3] = bf2f((u16)(av.y >> 16));
    aa[4] = bf2f((u16)(av.z & 0xFFFFu)); aa[5] = bf2f((u16)(av.z >> 16));
    aa[6] = bf2f((u16)(av.w & 0xFFFFu)); aa[7] = bf2f((u16)(av.w >> 16));
    #pragma unroll
    for (int mm = 0; mm < 8; mm++){
      float aj = aa[mm];
      int i4 = (m8*8 + mm)*8 + q*2;       // uint4 index: row*(64/8) ... 64 bf16 per row = 8 uint4
      uint4 w0 = w2q[i4], w1 = w2q[i4+1];
      out[0 ] += aj*__uint_as_float(w0.x << 16);
      out[1 ] += aj*__uint_as_float(w0.x & 0xFFFF0000u);
      out[2 ] += aj*__uint_as_float(w0.y << 16);
      out[3 ] += aj*__uint_as_float(w0.y & 0xFFFF0000u);
      out[4 ] += aj*__uint_as_float(w0.z << 16);
      out[5 ] += aj*__uint_as_float(w0.z & 0xFFFF0000u);
      out[6 ] += aj*__uint_as_float(w0.w << 16);
      out[7 ] += aj*__uint_as_float(w0.w & 0xFFFF0000u);
      out[8 ] += aj*__uint_as_float(w1.x << 16);
      out[9 ] += aj*__uint_as_float(w1.x & 0xFFFF0000u);
      out[10] += aj*__uint_as_float(w1.y << 16);
      out[11] += aj*__uint_as_float(w1.y & 0xFFFF0000u);
      out[12] += aj*__uint_as_float(w1.z << 16);
      out[13] += aj*__uint_as_float(w1.z & 0xFFFF0000u);
      out[14] += aj*__uint_as_float(w1.w << 16);
      out[15] += aj*__uint_as_float(w1.w & 0xFFFF0000u);
    }
  }
  size_t rb = (size_t)n*64 + cb;
  #pragma unroll
  for (int c4 = 0; c4 < 4; c4++){
    float4 hv = *(const float4*)&h[rb + c4*4];
    out[c4*4  ] += hv.x; out[c4*4+1] += hv.y;
    out[c4*4+2] += hv.z; out[c4*4+3] += hv.w;
  }
  if (!last){
    #pragma unroll
    for (int c4 = 0; c4 < 4; c4++)
      *(float4*)&h[rb + c4*4] = make_float4(out[c4*4], out[c4*4+1], out[c4*4+2], out[c4*4+3]);
    float s = 0.f;
    #pragma unroll
    for (int c = 0; c < 16; c++) s += out[c];
    s += __shfl_xor(s, 1); s += __shfl_xor(s, 2);
    float mean = s*(1.f/64.f);
    float vs = 0.f;
    #pragma unroll
    for (int c = 0; c < 16; c++){ float d = out[c]-mean; vs += d*d; }
    vs += __shfl_xor(vs, 1); vs += __shfl_xor(vs, 2);
    float rstd = rsqrtf(vs*(1.f/64.f) + 1e-5f);
    u32 pk[8];
    #pragma unroll
    for (int c2 = 0; c2 < 8; c2++){
      u16 lo = f2bf(fmaxf((out[c2*2  ]-mean)*rstd*cgn[cb+c2*2  ] + cbn[cb+c2*2  ], 0.f));
      u16 hi = f2bf(fmaxf((out[c2*2+1]-mean)*rstd*cgn[cb+c2*2+1] + cbn[cb+c2*2+1], 0.f));
      pk[c2] = (u32)lo | ((u32)hi << 16);
    }
    uint4* zp = (uint4*)&znext[rb];
    zp[0] = make_uint4(pk[0], pk[1], pk[2], pk[3]);
    zp[1] = make_uint4(pk[4], pk[5], pk[6], pk[7]);
  } else {
    int g = batch[n];
    #pragma unroll
    for (int c = 0; c < 16; c++) atomicAdd(&pooled[g*64 + cb + c], out[c]);
  }
}

// ---------------- pooled + var MLP -> t ; qkv for layer 0 ----------------
__global__ __launch_bounds__(128) void k_pool2(
    const float* __restrict__ pooled, const float* __restrict__ var_data,
    const float* __restrict__ v1W, const float* __restrict__ v1b,
    const float* __restrict__ v2W, const float* __restrict__ v2b,
    const float* __restrict__ v3W, const float* __restrict__ v3b,
    float* __restrict__ t, float* __restrict__ qkvout,
    const float* __restrict__ qW, const float* __restrict__ qb){
  __shared__ float vin[19], l1[16], l2[32], tr[128];
  int c = threadIdx.x, s = blockIdx.x;
  if (c < 19) vin[c] = var_data[s*19 + c];
  __syncthreads();
  if (c < 16){
    float a = v1b[c];
    for (int k = 0; k < 19; k++) a += vin[k]*v1W[k*16 + c];
    l1[c] = fmaxf(a, 0.f);
  }
  __syncthreads();
  if (c < 32){
    float a = v2b[c];
    for (int k = 0; k < 16; k++) a += l1[k]*v2W[k*32 + c];
    l2[c] = fmaxf(a, 0.f);
  }
  __syncthreads();
  float tv;
  if (c < 64) tv = pooled[s*64 + c];
  else {
    float a = v3b[c-64];
    for (int k = 0; k < 32; k++) a += l2[k]*v3W[k*64 + (c-64)];
    tv = a;
  }
  tr[c] = tv; t[s*128 + c] = tv;
  __syncthreads();
  #pragma unroll 1
  for (int r = 0; r < 3; r++){
    int col = r*128 + c;
    float a = qb[col];
    #pragma unroll 4
    for (int k = 0; k < 128; k++) a += tr[k]*qW[k*384 + col];
    qkvout[s*384 + col] = a;
  }
}

// ---------------- fused encoder layer: attention + oproj + LN1 + FF + LN2 (+ next qkv / head) ----------------
// grid = 256 blocks (one per row), 256 threads.
__global__ __launch_bounds__(256) void k_attrow(
    const float* __restrict__ qkv, float* __restrict__ t, float* __restrict__ qkvout,
    const float* __restrict__ outW, const float* __restrict__ outb,
    const float* __restrict__ l1g, const float* __restrict__ l1b,
    const float* __restrict__ f1W, const float* __restrict__ f1b,
    const float* __restrict__ f2W, const float* __restrict__ f2b,
    const float* __restrict__ l2g, const float* __restrict__ l2b,
    const float* __restrict__ qW, const float* __restrict__ qb,
    const float* __restrict__ hW, const float* __restrict__ hb2,
    float* __restrict__ dout, int last){
  __shared__ float kv[8448];        // staging: K/V tiles [64][132], weight k-tiles
  __shared__ float sc[8*260];       // scores [head][key]
  __shared__ float qrow[128], orow[128], strow[128], s1row[128], sfrow[128], t2row[128];
  __shared__ float red[4];
  int tid = threadIdx.x, s = blockIdx.x;
  if (tid < 128){ qrow[tid] = qkv[(size_t)s*384 + tid]; strow[tid] = t[(size_t)s*128 + tid]; }
  // ---- QK^T: 4 key tiles of 64 ----
  for (int tile = 0; tile < 4; tile++){
    __syncthreads();
    for (int i = tid; i < 8192; i += 256){
      int r = i >> 7, c = i & 127;
      kv[r*132 + c] = qkv[(size_t)(tile*64 + r)*384 + 128 + c];
    }
    __syncthreads();
    int j = tid >> 2, sub = tid & 3;      // 4 threads/key; heads sub and sub+4
    float d0 = 0.f, d1 = 0.f;
    #pragma unroll
    for (int d = 0; d < 16; d++){
      d0 += qrow[sub*16 + d]     * kv[j*132 + sub*16 + d];
      d1 += qrow[(sub+4)*16 + d] * kv[j*132 + (sub+4)*16 + d];
    }
    sc[sub*260     + tile*64 + j] = d0*0.25f;
    sc[(sub+4)*260 + tile*64 + j] = d1*0.25f;
  }
  __syncthreads();
  // ---- softmax per head (wave w handles heads 2w, 2w+1) ----
  {
    int wid = tid >> 6, lane = tid & 63;
    #pragma unroll
    for (int hh = 0; hh < 2; hh++){
      int hh2 = wid*2 + hh;
      float a0 = sc[hh2*260 + lane], a1 = sc[hh2*260 + 64 + lane];
      float a2 = sc[hh2*260 + 128 + lane], a3 = sc[hh2*260 + 192 + lane];
      float m = wmax64(fmaxf(fmaxf(a0,a1), fmaxf(a2,a3)));
      float e0 = __expf(a0-m), e1 = __expf(a1-m), e2 = __expf(a2-m), e3 = __expf(a3-m);
      float sum = wsum64((e0+e1)+(e2+e3));
      float inv = 1.f/sum;
      sc[hh2*260 + lane] = e0*inv; sc[hh2*260 + 64 + lane] = e1*inv;
      sc[hh2*260 + 128 + lane] = e2*inv; sc[hh2*260 + 192 + lane] = e3*inv;
    }
  }
  // ---- PV: 4 value tiles ----
  float o = 0.f;
  int hme = (tid & 127) >> 4;
  for (int tile = 0; tile < 4; tile++){
    __syncthreads();
    for (int i = tid; i < 8192; i += 256){
      int r = i >> 7, c = i & 127;
      kv[r*132 + c] = qkv[(size_t)(tile*64 + r)*384 + 256 + c];
    }
    __syncthreads();
    if (tid < 128){
      #pragma unroll 4
      for (int j = 0; j < 64; j++)
        o += sc[hme*260 + tile*64 + j] * kv[j*132 + tid];
    }
  }
  if (tid < 128) orow[tid] = o;
  // ---- oproj (staged outW k-tiles) + residual + LN1 ----
  float acc = (tid < 128) ? outb[tid] : 0.f;
  for (int kt = 0; kt < 4; kt++){
    __syncthreads();
    for (int i = tid; i < 4096; i += 256) kv[i] = outW[(size_t)kt*4096 + i];
    __syncthreads();
    if (tid < 128){
      #pragma unroll 8
      for (int kk = 0; kk < 32; kk++) acc += orow[kt*32 + kk]*kv[kk*128 + tid];
    }
  }
  if (tid < 128) acc += strow[tid];
  float mean = bsum256((tid < 128) ? acc : 0.f, red)*(1.f/128.f);
  float d0v = (tid < 128) ? (acc - mean) : 0.f;
  float var = bsum256(d0v*d0v, red)*(1.f/128.f);
  float t1 = 0.f;
  if (tid < 128){
    t1 = d0v*rsqrtf(var + 1e-5f)*l1g[tid] + l1b[tid];
    s1row[tid] = t1;
  }
  // ---- FF1 + gelu ----
  float f = (tid < 128) ? f1b[tid] : 0.f;
  for (int kt = 0; kt < 4; kt++){
    __syncthreads();
    for (int i = tid; i < 4096; i += 256) kv[i] = f1W[(size_t)kt*4096 + i];
    __syncthreads();
    if (tid < 128){
      #pragma unroll 8
      for (int kk = 0; kk < 32; kk++) f += s1row[kt*32 + kk]*kv[kk*128 + tid];
    }
  }
  if (tid < 128){
    f = 0.5f*f*(1.f + erff(f*0.70710678118654752f));
    sfrow[tid] = f;
  }
  // ---- FF2 + residual + LN2 ----
  float g = (tid < 128) ? f2b[tid] : 0.f;
  for (int kt = 0; kt < 4; kt++){
    __syncthreads();
    for (int i = tid; i < 4096; i += 256) kv[i] = f2W[(size_t)kt*4096 + i];
    __syncthreads();
    if (tid < 128){
      #pragma unroll 8
      for (int kk = 0; kk < 32; kk++) g += sfrow[kt*32 + kk]*kv[kk*128 + tid];
    }
  }
  if (tid < 128) g += t1;
  float mean2 = bsum256((tid < 128) ? g : 0.f, red)*(1.f/128.f);
  float d2v = (tid < 128) ? (g - mean2) : 0.f;
  float var2 = bsum256(d2v*d2v, red)*(1.f/128.f);
  if (tid < 128){
    float t2 = d2v*rsqrtf(var2 + 1e-5f)*l2g[tid] + l2b[tid];
    t[(size_t)s*128 + tid] = t2;
    t2row[tid] = t2;
  }
  __syncthreads();
  if (!last){
    // next-layer qkv: 384 cols; thread handles col tid and (tid<128 ? 256+tid : none)
    float a0 = qb[tid];
    float a1 = (tid < 128) ? qb[256 + tid] : 0.f;
    for (int kt = 0; kt < 8; kt++){
      __syncthreads();
      for (int i = tid; i < 6144; i += 256) kv[i] = qW[(size_t)kt*6144 + i];
      __syncthreads();
      #pragma unroll 4
      for (int kk = 0; kk < 16; kk++){
        float tv = t2row[kt*16 + kk];
        a0 += tv*kv[kk*384 + tid];
        if (tid < 128) a1 += tv*kv[kk*384 + 256 + tid];
      }
    }
    qkvout[(size_t)s*384 + tid] = a0;
    if (tid < 128) qkvout[(size_t)s*384 + 256 + tid] = a1;
  } else {
    if (tid < 2){
      float a = hb2[tid];
      for (int k = 0; k < 128; k++) a += t2row[k]*hW[k*2 + tid];
      dout[s*2 + tid] = a;
    }
  }
}

// ---------------- host ----------------
extern "C" void kernel_launch(void* const* d_in, const int* in_sizes, int n_in,
                              void* d_out, int out_size, void* d_ws, size_t ws_size,
                              hipStream_t stream){
  const float* x       = (const float*)d_in[0];
  const int*   ei      = (const int*)  d_in[1];
  const int*   batch   = (const int*)  d_in[2];
  const float* var_d   = (const float*)d_in[3];
  const float* encW    = (const float*)d_in[4];
  const float* encb    = (const float*)d_in[5];
  const float* ln_g    = (const float*)d_in[6];
  const float* ln_b    = (const float*)d_in[7];
  const float* tparam  = (const float*)d_in[8];
  const float* m1W     = (const float*)d_in[9];
  const float* m1b     = (const float*)d_in[10];
  const float* mng     = (const float*)d_in[11];
  const float* mnb     = (const float*)d_in[12];
  const float* m2W     = (const float*)d_in[13];
  const float* m2b     = (const float*)d_in[14];
  const float* v1W     = (const float*)d_in[15];
  const float* v1b     = (const float*)d_in[16];
  const float* v2W     = (const float*)d_in[17];
  const float* v2b     = (const float*)d_in[18];
  const float* v3W     = (const float*)d_in[19];
  const float* v3b     = (const float*)d_in[20];
  const float* qkvW    = (const float*)d_in[21];
  const float* qkvB    = (const float*)d_in[22];
  const float* outW    = (const float*)d_in[23];
  const float* outb    = (const float*)d_in[24];
  const float* l1g     = (const float*)d_in[25];
  const float* l1b     = (const float*)d_in[26];
  const float* f1W     = (const float*)d_in[27];
  const float* f1b     = (const float*)d_in[28];
  const float* f2W     = (const float*)d_in[29];
  const float* f2b     = (const float*)d_in[30];
  const float* l2g     = (const float*)d_in[31];
  const float* l2b     = (const float*)d_in[32];
  const float* headW   = (const float*)d_in[33];
  const float* headB   = (const float*)d_in[34];
  float* dout = (float*)d_out;

  char* wsb = (char*)d_ws;
  size_t off = 0;
  auto nxt = [&](size_t bytes)->void*{
    void* p = wsb + off;
    off += (bytes + 255) & ~(size_t)255;
    return p;
  };
  float* h      = (float*)nxt((size_t)NODES*64*4);
  u16*   z      = (u16*)  nxt((size_t)NODES*64*2);
  u16*   u      = (u16*)  nxt((size_t)NODES*64*2);
  u16*   act    = (u16*)  nxt((size_t)NODES*128*2);
  int*   rowptr = (int*)  nxt((size_t)(NODES+1)*4);
  int*   cursor = (int*)  nxt((size_t)NODES*4);
  int*   counts = (int*)  nxt((size_t)NODES*4);
  int*   bsums  = (int*)  nxt(64*4);
  int*   boffs  = (int*)  nxt(64*4);
  int*   esrc   = (int*)  nxt((size_t)EDGES*4);
  float* pooled = (float*)nxt((size_t)NG*64*4);
  float* tbuf   = (float*)nxt((size_t)NG*128*4);
  float* qkv0   = (float*)nxt((size_t)NG*384*4);
  float* qkv1   = (float*)nxt((size_t)NG*384*4);
  float* qkvb[2] = { qkv0, qkv1 };

  const int* srcp = ei;
  const int* dstp = ei + EDGES;

  k_zero_i <<<391, 256, 0, stream>>>(counts, NODES);
  k_hist   <<<4688, 256, 0, stream>>>(dstp, counts);
  k_scan1  <<<49, 256, 0, stream>>>(counts, rowptr, bsums);
  k_scan2  <<<1, 64, 0, stream>>>(bsums, boffs, 49);
  k_scan3  <<<391, 256, 0, stream>>>(rowptr, cursor, boffs);
  k_scatter<<<4688, 256, 0, stream>>>(srcp, dstp, cursor, esrc);
  k_zero_f <<<64, 256, 0, stream>>>(pooled, NG*64);
  k_enc    <<<391, 256, 0, stream>>>(x, encW, encb, ln_g, ln_b, h, z);

  for (int i = 0; i < 6; i++){
    int last = (i == 5);
    k_agg <<<25000, 256, 0, stream>>>(z, u, rowptr, esrc, tparam, i);
    k_mlpa<<<782, 256, 0, stream>>>(u, act,
        m1W + i*8192, m1b + i*128, mng + i*128, mnb + i*128);
    k_mlpb<<<1563, 256, 0, stream>>>(act, h, z, pooled, batch,
        m2W + i*8192, m2b + i*64,
        ln_g + (last ? 0 : (i+1)*64), ln_b + (last ? 0 : (i+1)*64), last);
  }

  k_pool2<<<NG, 128, 0, stream>>>(pooled, var_d, v1W, v1b, v2W, v2b, v3W, v3b,
                                  tbuf, qkv0, qkvW, qkvB);

  for (int i = 0; i < 6; i++){
    int last = (i == 5);
    k_attrow<<<NG, 256, 0, stream>>>(qkvb[i & 1], tbuf, qkvb[(i + 1) & 1],
        outW + i*16384, outb + i*128, l1g + i*128, l1b + i*128,
        f1W + i*16384, f1b + i*128, f2W + i*16384, f2b + i*128,
        l2g + i*128, l2b + i*128,
        qkvW + (size_t)(last ? 0 : (i+1))*49152, qkvB + (last ? 0 : (i+1))*384,
        headW, headB, dout, last);
  }
}